// Round 1
// baseline (150.859 us; speedup 1.0000x reference)
//
#include <hip/hip_runtime.h>
#include <hip/hip_bf16.h>

#define NB   8192   // batch
#define NS   10     // neighbor seq len
#define NT   3      // node types
#define NN   65536  // table size
#define ND   128    // embed dim
#define NL   2      // layers

typedef __attribute__((ext_vector_type(8))) short bf16x8;
typedef __attribute__((ext_vector_type(4))) float f32x4;

__device__ __forceinline__ unsigned int f2bf(float f) {
    unsigned int x = __float_as_uint(f);
    return (x + 0x7FFFu + ((x >> 16) & 1u)) >> 16;   // RNE fp32 -> bf16 bits
}
__device__ __forceinline__ float fast_tanh(float x) {
    float e = __expf(2.0f * x);
    return 1.0f - __fdividef(2.0f, e + 1.0f);
}

// ---------------------------------------------------------------------------
// RNN kernel: grid = NL*NT*64 blocks, 256 threads (4 waves).
// Block owns (l, t, 128 batch rows). Computes agg[l][t][e][b] = mean_s h_s.
// W2 = [Wih;Whh] held in registers as MFMA A-fragments (per-wave e-range 32).
// X_s and H staged in LDS (bf16, XOR-swizzled 16B chunks). MFMA computes
// out^T = W2 * Z^T so C-frag holds 4 consecutive e at fixed row -> b64 H write.
// ---------------------------------------------------------------------------
__global__ __launch_bounds__(256, 2)
void rnn_kernel(const float* __restrict__ emb, const float* __restrict__ Wih,
                const float* __restrict__ Whh, const float* __restrict__ bih,
                const float* __restrict__ bhh, const int* __restrict__ nidx,
                float* __restrict__ agg)
{
    __shared__ __align__(16) unsigned short Xs[128 * 128];
    __shared__ __align__(16) unsigned short Hs[128 * 128];
    char* xb = (char*)Xs;
    char* hb = (char*)Hs;

    const int bid = blockIdx.x;
    const int l   = bid / (NT * 64);
    const int t   = (bid / 64) % NT;
    const int b0  = (bid % 64) * 128;

    const int tid  = threadIdx.x;
    const int w    = tid >> 6;
    const int lane = tid & 63;
    const int l16  = lane & 15;
    const int lg   = lane >> 4;
    const int e0   = w * 32;

    const float* Wih_lt = Wih + (size_t)(l * NT + t) * ND * ND;
    const float* Whh_lt = Whh + (size_t)(l * NT + t) * ND * ND;
    const float* bih_lt = bih + (size_t)(l * NT + t) * ND;
    const float* bhh_lt = bhh + (size_t)(l * NT + t) * ND;

    // A-fragments: rows e = e0 + mt*16 + l16, k-chunk kc (kc<4: Wih d, kc>=4: Whh d)
    bf16x8 Af[2][8];
    #pragma unroll
    for (int mt = 0; mt < 2; ++mt) {
        #pragma unroll
        for (int kc = 0; kc < 8; ++kc) {
            const float* Wsrc = (kc < 4) ? Wih_lt : Whh_lt;
            const float* srcp = Wsrc + (size_t)(e0 + mt * 16 + l16) * ND + (kc & 3) * 32 + lg * 8;
            float4 p0 = *(const float4*)(srcp);
            float4 p1 = *(const float4*)(srcp + 4);
            bf16x8 v;
            v[0] = (short)f2bf(p0.x); v[1] = (short)f2bf(p0.y);
            v[2] = (short)f2bf(p0.z); v[3] = (short)f2bf(p0.w);
            v[4] = (short)f2bf(p1.x); v[5] = (short)f2bf(p1.y);
            v[6] = (short)f2bf(p1.z); v[7] = (short)f2bf(p1.w);
            Af[mt][kc] = v;
        }
    }

    float bias[2][4];
    #pragma unroll
    for (int mt = 0; mt < 2; ++mt)
        #pragma unroll
        for (int i = 0; i < 4; ++i) {
            int e = e0 + mt * 16 + lg * 4 + i;
            bias[mt][i] = bih_lt[e] + bhh_lt[e];
        }

    f32x4 zero4; zero4[0] = 0.f; zero4[1] = 0.f; zero4[2] = 0.f; zero4[3] = 0.f;

    f32x4 Ag[8][2];
    #pragma unroll
    for (int nt = 0; nt < 8; ++nt) { Ag[nt][0] = zero4; Ag[nt][1] = zero4; }

    const int srow  = tid >> 1;     // staging row 0..127
    const int shalf = tid & 1;      // which 64-d half
    const int ssw   = srow & 7;     // swizzle key

    for (int s = 0; s < NS; ++s) {
        // ---- stage X_s: gather + fp32->bf16 + swizzled LDS store ----
        {
            int idx = nidx[((size_t)t * NB + b0 + srow) * NS + s];
            const float* src = emb + ((size_t)t * NN + idx) * ND + shalf * 64;
            #pragma unroll
            for (int c = 0; c < 8; ++c) {
                float4 p0 = *(const float4*)(src + c * 8);
                float4 p1 = *(const float4*)(src + c * 8 + 4);
                int4 pk;
                pk.x = (int)(f2bf(p0.x) | (f2bf(p0.y) << 16));
                pk.y = (int)(f2bf(p0.z) | (f2bf(p0.w) << 16));
                pk.z = (int)(f2bf(p1.x) | (f2bf(p1.y) << 16));
                pk.w = (int)(f2bf(p1.z) | (f2bf(p1.w) << 16));
                int chunk = (shalf * 8 + c) ^ ssw;
                *(int4*)(xb + srow * 256 + (chunk << 4)) = pk;
            }
        }
        __syncthreads();   // Xs ready; prior H writes ordered for all readers

        // ---- compute: acc[nt][mt] = W2-rows x Z-rows (K = 256: X then H) ----
        f32x4 acc[8][2];
        #pragma unroll
        for (int nt = 0; nt < 8; ++nt) { acc[nt][0] = zero4; acc[nt][1] = zero4; }

        #pragma unroll
        for (int nt = 0; nt < 8; ++nt) {
            const int r  = nt * 16 + l16;   // B-frag: n = row index of Z
            const int rx = r & 7;
            #pragma unroll
            for (int kc = 0; kc < 8; ++kc) {
                if (kc < 4 || s > 0) {      // h0 == 0: skip H-matmul at s==0
                    const char* buf = (kc < 4) ? xb : hb;
                    int chunk = ((kc & 3) * 4 + lg) ^ rx;
                    bf16x8 bf = *(const bf16x8*)(buf + r * 256 + (chunk << 4));
                    acc[nt][0] = __builtin_amdgcn_mfma_f32_16x16x32_bf16(Af[0][kc], bf, acc[nt][0], 0, 0, 0);
                    acc[nt][1] = __builtin_amdgcn_mfma_f32_16x16x32_bf16(Af[1][kc], bf, acc[nt][1], 0, 0, 0);
                }
            }
        }
        __syncthreads();   // all X/H reads complete before H is overwritten

        // ---- tanh + agg accumulate + packed H writeback ----
        #pragma unroll
        for (int nt = 0; nt < 8; ++nt) {
            const int r  = nt * 16 + l16;
            const int rx = r & 7;
            #pragma unroll
            for (int mt = 0; mt < 2; ++mt) {
                f32x4 h;
                #pragma unroll
                for (int i = 0; i < 4; ++i)
                    h[i] = fast_tanh(acc[nt][mt][i] + bias[mt][i]);
                Ag[nt][mt] += h;
                int2 pk;
                pk.x = (int)(f2bf(h[0]) | (f2bf(h[1]) << 16));
                pk.y = (int)(f2bf(h[2]) | (f2bf(h[3]) << 16));
                int estart = e0 + mt * 16 + lg * 4;       // 4 consecutive e, fixed row r
                int chunk  = (estart >> 3) ^ rx;
                *(int2*)(hb + r * 256 + (chunk << 4) + (estart & 7) * 2) = pk;
            }
        }
        // no barrier needed: next stage touches Xs only; next __syncthreads orders Hs
    }

    // agg stored transposed: agg[l][t][e][b] (lane-consecutive b -> coalesced)
    float* aggp = agg + (size_t)(l * NT + t) * ND * NB;
    #pragma unroll
    for (int nt = 0; nt < 8; ++nt) {
        int b = b0 + nt * 16 + l16;
        #pragma unroll
        for (int mt = 0; mt < 2; ++mt)
            #pragma unroll
            for (int i = 0; i < 4; ++i) {
                int e = e0 + mt * 16 + lg * 4 + i;
                aggp[(size_t)e * NB + b] = Ag[nt][mt][i] * 0.1f;
            }
    }
}

// ---------------------------------------------------------------------------
// Attention kernel: thread per batch row. scores -> softmax(4) -> weighted sum
// -> leaky_relu. l==0 reads cur from emb[0][ids]; in-place update of cur.
// ---------------------------------------------------------------------------
__global__ __launch_bounds__(64)
void att_kernel(const float* __restrict__ emb, const int* __restrict__ ids,
                const float* __restrict__ w_att, const float* __restrict__ agg,
                float* __restrict__ cur, const int l)
{
    const int b = blockIdx.x * 64 + threadIdx.x;
    const float* waH  = w_att + l * 2 * ND;
    const float* waT  = waH + ND;
    const float* crow = (l == 0) ? (emb + (size_t)ids[b] * ND) : (cur + (size_t)b * ND);
    const float* aggl = agg + (size_t)l * NT * ND * NB;

    float dH = 0.f, dc = 0.f;
    float dt[3] = {0.f, 0.f, 0.f};
    for (int d = 0; d < ND; d += 4) {
        float4 c4 = *(const float4*)(crow + d);
        float4 wh = *(const float4*)(waH + d);
        float4 wt = *(const float4*)(waT + d);
        dH += c4.x * wh.x + c4.y * wh.y + c4.z * wh.z + c4.w * wh.w;
        dc += c4.x * wt.x + c4.y * wt.y + c4.z * wt.z + c4.w * wt.w;
        #pragma unroll
        for (int tt = 0; tt < 3; ++tt) {
            const float* ap = aggl + (size_t)(tt * ND + d) * NB + b;
            dt[tt] += ap[0] * wt.x + ap[(size_t)NB] * wt.y
                    + ap[2 * (size_t)NB] * wt.z + ap[3 * (size_t)NB] * wt.w;
        }
    }
    float s0 = dH + dc, s1 = dH + dt[0], s2 = dH + dt[1], s3 = dH + dt[2];
    float m  = fmaxf(fmaxf(s0, s1), fmaxf(s2, s3));
    float q0 = __expf(s0 - m), q1 = __expf(s1 - m), q2 = __expf(s2 - m), q3 = __expf(s3 - m);
    float inv = __fdividef(1.0f, q0 + q1 + q2 + q3);
    float w0 = q0 * inv, w1 = q1 * inv, w2 = q2 * inv, w3 = q3 * inv;

    float* orow = cur + (size_t)b * ND;
    for (int d = 0; d < ND; d += 4) {
        float4 c4 = *(const float4*)(crow + d);
        float4 o;
        #pragma unroll
        for (int j = 0; j < 4; ++j) {
            const float* ap = aggl + (size_t)(d + j) * NB + b;
            float v = w0 * ((const float*)&c4)[j]
                    + w1 * ap[0]
                    + w2 * ap[(size_t)ND * NB]
                    + w3 * ap[2 * (size_t)ND * NB];
            ((float*)&o)[j] = (v > 0.f) ? v : 0.01f * v;
        }
        *(float4*)(orow + d) = o;
    }
}

extern "C" void kernel_launch(void* const* d_in, const int* in_sizes, int n_in,
                              void* d_out, int out_size, void* d_ws, size_t ws_size,
                              hipStream_t stream)
{
    const float* emb  = (const float*)d_in[0];
    const float* Wih  = (const float*)d_in[1];
    const float* Whh  = (const float*)d_in[2];
    const float* bih  = (const float*)d_in[3];
    const float* bhh  = (const float*)d_in[4];
    const float* watt = (const float*)d_in[5];
    const int*   ids  = (const int*)d_in[6];
    const int*   nidx = (const int*)d_in[7];

    float* cur = (float*)d_out;            // [B][D] fp32, final output
    float* agg = (float*)d_ws;             // [L][T][D][B] fp32 = 24 MB

    rnn_kernel<<<dim3(NL * NT * 64), dim3(256), 0, stream>>>(emb, Wih, Whh, bih, bhh, nidx, agg);
    att_kernel<<<dim3(NB / 64), dim3(64), 0, stream>>>(emb, ids, watt, agg, cur, 0);
    att_kernel<<<dim3(NB / 64), dim3(64), 0, stream>>>(emb, ids, watt, agg, cur, 1);
}

// Round 4
// 93.271 us; speedup vs baseline: 1.6174x; 1.6174x over previous
//
#include <hip/hip_runtime.h>
#include <hip/hip_bf16.h>

#define NB   8192   // batch
#define NS   10     // neighbor seq len
#define NT   3      // node types
#define NN   65536  // table size
#define ND   128    // embed dim
#define NL   2      // layers

typedef __attribute__((ext_vector_type(8))) short bf16x8;
typedef __attribute__((ext_vector_type(4))) float f32x4;

__device__ __forceinline__ unsigned int f2bf(float f) {
    unsigned int x = __float_as_uint(f);
    return (x + 0x7FFFu + ((x >> 16) & 1u)) >> 16;   // RNE fp32 -> bf16 bits
}
__device__ __forceinline__ unsigned int pk2(float lo, float hi) {
    unsigned int r;
    asm("v_cvt_pk_bf16_f32 %0, %1, %2" : "=v"(r) : "v"(lo), "v"(hi));
    return r;
}
__device__ __forceinline__ float fast_tanh(float x) {
    float e = __expf(2.0f * x);
    return 1.0f - __fdividef(2.0f, e + 1.0f);
}

// ---------------------------------------------------------------------------
// RNN kernel: grid = NL*NT*128 blocks, 256 threads (4 waves).
// Block owns (l, t, 64 batch rows). Wave w owns e-range [w*32, w*32+32).
// W2 = [Wih;Whh] in registers as MFMA A-fragments. X_s and H staged in LDS
// (bf16, XOR-swizzled 16B chunks). Next-step X gather prefetched into
// registers before barrier (T14) so HBM latency hides under compute.
// ---------------------------------------------------------------------------
__global__ __launch_bounds__(256, 2)
void rnn_kernel(const float* __restrict__ emb, const float* __restrict__ Wih,
                const float* __restrict__ Whh, const float* __restrict__ bih,
                const float* __restrict__ bhh, const int* __restrict__ nidx,
                float* __restrict__ agg)
{
    __shared__ __align__(16) unsigned short Xs[64 * 128];   // 16 KB
    __shared__ __align__(16) unsigned short Hs[64 * 128];   // 16 KB
    char* xb = (char*)Xs;
    char* hb = (char*)Hs;

    const int bid = blockIdx.x;
    const int l   = bid / (NT * 128);
    const int t   = (bid / 128) % NT;
    const int b0  = (bid % 128) * 64;

    const int tid  = threadIdx.x;
    const int w    = tid >> 6;
    const int lane = tid & 63;
    const int l16  = lane & 15;
    const int lg   = lane >> 4;
    const int e0   = w * 32;
    const int rx   = l16 & 7;        // row swizzle key (row%8 == l16%8, rows stride 16)

    const float* Wih_lt = Wih + (size_t)(l * NT + t) * ND * ND;
    const float* Whh_lt = Whh + (size_t)(l * NT + t) * ND * ND;
    const float* bih_lt = bih + (size_t)(l * NT + t) * ND;
    const float* bhh_lt = bhh + (size_t)(l * NT + t) * ND;

    // staging geometry: 4 threads per row, 32 d each
    const int srow = tid >> 2;       // 0..63
    const int sq   = tid & 3;        // d-quarter
    const int ssw  = srow & 7;       // swizzle key

    const int* ip = nidx + ((size_t)t * NB + b0 + srow) * NS;

    // ---- prefetch s=0 gather ----
    float4 P[8];
    {
        int idx0 = ip[0];
        const float* src = emb + ((size_t)t * NN + idx0) * ND + sq * 32;
        #pragma unroll
        for (int c = 0; c < 4; ++c) {
            P[2 * c]     = *(const float4*)(src + c * 8);
            P[2 * c + 1] = *(const float4*)(src + c * 8 + 4);
        }
    }

    // ---- A-fragments: rows e = e0 + mt*16 + l16, k-chunk kc (kc<4: Wih, else Whh) ----
    bf16x8 Af[2][8];
    #pragma unroll
    for (int mt = 0; mt < 2; ++mt) {
        #pragma unroll
        for (int kc = 0; kc < 8; ++kc) {
            const float* Wsrc = (kc < 4) ? Wih_lt : Whh_lt;
            const float* srcp = Wsrc + (size_t)(e0 + mt * 16 + l16) * ND + (kc & 3) * 32 + lg * 8;
            float4 p0 = *(const float4*)(srcp);
            float4 p1 = *(const float4*)(srcp + 4);
            bf16x8 v;
            v[0] = (short)f2bf(p0.x); v[1] = (short)f2bf(p0.y);
            v[2] = (short)f2bf(p0.z); v[3] = (short)f2bf(p0.w);
            v[4] = (short)f2bf(p1.x); v[5] = (short)f2bf(p1.y);
            v[6] = (short)f2bf(p1.z); v[7] = (short)f2bf(p1.w);
            Af[mt][kc] = v;
        }
    }

    float bias[2][4];
    #pragma unroll
    for (int mt = 0; mt < 2; ++mt)
        #pragma unroll
        for (int i = 0; i < 4; ++i) {
            int e = e0 + mt * 16 + lg * 4 + i;
            bias[mt][i] = bih_lt[e] + bhh_lt[e];
        }

    f32x4 zero4; zero4[0] = 0.f; zero4[1] = 0.f; zero4[2] = 0.f; zero4[3] = 0.f;
    f32x4 Ag[4][2];
    #pragma unroll
    for (int nt = 0; nt < 4; ++nt) { Ag[nt][0] = zero4; Ag[nt][1] = zero4; }

    for (int s = 0; s < NS; ++s) {
        // ---- pack prefetched X_s -> swizzled LDS store ----
        #pragma unroll
        for (int c = 0; c < 4; ++c) {
            int4 pk;
            pk.x = (int)pk2(P[2 * c].x,     P[2 * c].y);
            pk.y = (int)pk2(P[2 * c].z,     P[2 * c].w);
            pk.z = (int)pk2(P[2 * c + 1].x, P[2 * c + 1].y);
            pk.w = (int)pk2(P[2 * c + 1].z, P[2 * c + 1].w);
            int chunk = (sq * 4 + c) ^ ssw;
            *(int4*)(xb + srow * 256 + (chunk << 4)) = pk;
        }
        // ---- issue next-step gather now; lands during compute (T14) ----
        if (s + 1 < NS) {
            int idxn = ip[s + 1];
            const float* src = emb + ((size_t)t * NN + idxn) * ND + sq * 32;
            #pragma unroll
            for (int c = 0; c < 4; ++c) {
                P[2 * c]     = *(const float4*)(src + c * 8);
                P[2 * c + 1] = *(const float4*)(src + c * 8 + 4);
            }
        }
        __syncthreads();   // Xs ready; prior H writes ordered for all readers

        // ---- acc[nt][mt] = W2-rows x Z-rows (K = 256: X then H) ----
        f32x4 acc[4][2];
        #pragma unroll
        for (int nt = 0; nt < 4; ++nt) { acc[nt][0] = zero4; acc[nt][1] = zero4; }

        #pragma unroll
        for (int nt = 0; nt < 4; ++nt) {
            const int r = nt * 16 + l16;
            #pragma unroll
            for (int kc = 0; kc < 8; ++kc) {
                if (kc < 4 || s > 0) {      // h0 == 0: skip H-matmul at s==0
                    const char* buf = (kc < 4) ? xb : hb;
                    int chunk = ((kc & 3) * 4 + lg) ^ rx;
                    bf16x8 bf = *(const bf16x8*)(buf + r * 256 + (chunk << 4));
                    acc[nt][0] = __builtin_amdgcn_mfma_f32_16x16x32_bf16(Af[0][kc], bf, acc[nt][0], 0, 0, 0);
                    acc[nt][1] = __builtin_amdgcn_mfma_f32_16x16x32_bf16(Af[1][kc], bf, acc[nt][1], 0, 0, 0);
                }
            }
        }
        __syncthreads();   // all X/H reads complete before Xs/Hs overwritten

        // ---- tanh + agg accumulate + packed H writeback ----
        #pragma unroll
        for (int nt = 0; nt < 4; ++nt) {
            const int r = nt * 16 + l16;
            #pragma unroll
            for (int mt = 0; mt < 2; ++mt) {
                f32x4 h;
                #pragma unroll
                for (int i = 0; i < 4; ++i)
                    h[i] = fast_tanh(acc[nt][mt][i] + bias[mt][i]);
                Ag[nt][mt] += h;
                int2 pk;
                pk.x = (int)pk2(h[0], h[1]);
                pk.y = (int)pk2(h[2], h[3]);
                int estart = e0 + mt * 16 + lg * 4;   // 4 consecutive e, fixed row r
                int chunk  = (estart >> 3) ^ rx;
                *(int2*)(hb + r * 256 + (chunk << 4) + (estart & 7) * 2) = pk;
            }
        }
        // next iteration's first __syncthreads orders these H writes for readers
    }

    // agg[l][t][b][e]: lane writes float4 of 4 consecutive e at its row b
    float* aggp = agg + ((size_t)(l * NT + t) * NB + b0) * ND;
    #pragma unroll
    for (int nt = 0; nt < 4; ++nt) {
        int b = nt * 16 + l16;
        #pragma unroll
        for (int mt = 0; mt < 2; ++mt) {
            f32x4 v = Ag[nt][mt] * 0.1f;
            *(f32x4*)(aggp + (size_t)b * ND + e0 + mt * 16 + lg * 4) = v;
        }
    }
}

// ---------------------------------------------------------------------------
// Attention: one wave per batch row (lane covers d and d+64). 5 dots via
// shuffle reduce, softmax(4), weighted sum, leaky_relu. 2048 blocks x 256.
// ---------------------------------------------------------------------------
__global__ __launch_bounds__(256)
void att_kernel(const float* __restrict__ emb, const int* __restrict__ ids,
                const float* __restrict__ w_att, const float* __restrict__ agg,
                float* __restrict__ cur, const int l)
{
    const int wid  = threadIdx.x >> 6;
    const int lane = threadIdx.x & 63;
    const int b    = blockIdx.x * 4 + wid;

    const float* waH  = w_att + l * 2 * ND;
    const float* waT  = waH + ND;
    const float* crow = (l == 0) ? (emb + (size_t)ids[b] * ND) : (cur + (size_t)b * ND);
    const float* ab   = agg + ((size_t)(l * NT) * NB + b) * ND;   // + tt*NB*ND

    const float c1 = crow[lane], c2 = crow[lane + 64];
    const float h1 = waH[lane],  h2 = waH[lane + 64];
    const float t1 = waT[lane],  t2 = waT[lane + 64];
    float g1[3], g2[3];
    #pragma unroll
    for (int tt = 0; tt < 3; ++tt) {
        g1[tt] = ab[(size_t)tt * NB * ND + lane];
        g2[tt] = ab[(size_t)tt * NB * ND + lane + 64];
    }

    float dH = c1 * h1 + c2 * h2;
    float dc = c1 * t1 + c2 * t2;
    float d0 = g1[0] * t1 + g2[0] * t2;
    float d1 = g1[1] * t1 + g2[1] * t2;
    float d2 = g1[2] * t1 + g2[2] * t2;
    #pragma unroll
    for (int off = 32; off > 0; off >>= 1) {
        dH += __shfl_xor(dH, off);
        dc += __shfl_xor(dc, off);
        d0 += __shfl_xor(d0, off);
        d1 += __shfl_xor(d1, off);
        d2 += __shfl_xor(d2, off);
    }

    float s0 = dH + dc, s1 = dH + d0, s2 = dH + d1, s3 = dH + d2;
    float m  = fmaxf(fmaxf(s0, s1), fmaxf(s2, s3));
    float q0 = __expf(s0 - m), q1 = __expf(s1 - m), q2 = __expf(s2 - m), q3 = __expf(s3 - m);
    float inv = __fdividef(1.0f, q0 + q1 + q2 + q3);
    float w0 = q0 * inv, w1 = q1 * inv, w2 = q2 * inv, w3 = q3 * inv;

    float o1 = w0 * c1 + w1 * g1[0] + w2 * g1[1] + w3 * g1[2];
    float o2 = w0 * c2 + w1 * g2[0] + w2 * g2[1] + w3 * g2[2];
    o1 = (o1 > 0.f) ? o1 : 0.01f * o1;
    o2 = (o2 > 0.f) ? o2 : 0.01f * o2;

    float* orow = cur + (size_t)b * ND;
    orow[lane]      = o1;
    orow[lane + 64] = o2;
}

extern "C" void kernel_launch(void* const* d_in, const int* in_sizes, int n_in,
                              void* d_out, int out_size, void* d_ws, size_t ws_size,
                              hipStream_t stream)
{
    const float* emb  = (const float*)d_in[0];
    const float* Wih  = (const float*)d_in[1];
    const float* Whh  = (const float*)d_in[2];
    const float* bih  = (const float*)d_in[3];
    const float* bhh  = (const float*)d_in[4];
    const float* watt = (const float*)d_in[5];
    const int*   ids  = (const int*)d_in[6];
    const int*   nidx = (const int*)d_in[7];

    float* cur = (float*)d_out;            // [B][D] fp32, final output
    float* agg = (float*)d_ws;             // [L][T][B][D] fp32 = 25 MB

    rnn_kernel<<<dim3(NL * NT * 128), dim3(256), 0, stream>>>(emb, Wih, Whh, bih, bhh, nidx, agg);
    att_kernel<<<dim3(NB / 4), dim3(256), 0, stream>>>(emb, ids, watt, agg, cur, 0);
    att_kernel<<<dim3(NB / 4), dim3(256), 0, stream>>>(emb, ids, watt, agg, cur, 1);
}